// Round 11
// baseline (1027.032 us; speedup 1.0000x reference)
//
#include <hip/hip_runtime.h>
#include <cstdint>
#include <cstddef>

// ---------------------------------------------------------------------------
// SpikingCoreFlow: bit-exact replication of the JAX reference on MI355X.
//
// Dims: B=128, D_in=1024, n_cores=64, N=256, A=256, n_out=10, cycles=32,
// pool_width = 17410.
//
// Pool "Pb" (bytes, rows of 128 = B): spikes rows [0,32768) = t*1024+d;
// buffer ping A [32768,49152), pong B [49152,65536); zeros 65536; ones 65537.
// Cycle t reads parity A if t even, writes the other.
//
// Exactness (verified R2-R10, absmax == 0.0):
//  - threefry2x32, jax_threefry_partitionable=True semantics.
//  - einsum = single ascending-a fused-FMA chain from 0 per (c,b,n); memb+=E
//    is one more rounded add. Mask operands are exactly {0.0f,1.0f};
//    v_pk_fma_f32 = 2 independent IEEE FMAs -> per-(n,b) chain unchanged.
//
// Perf journal (core dispatch):
//  UNIFIED LESSON (R3-R10): a wave-SHARED operand through a per-lane pipe
//  pays 64x: uniform ds_read_b128 = 12cy for 16B useful (R7/8: 49K cy/CU =
//  20us); "uniform" global_load that fails s_load promotion = full 1KB
//  return (R10: 4MB/CU = 27us). Scalar K$ path works only with provably
//  uniform addresses (blockIdx-only, no tid) + chunk-batched lgkm waits.
//  R11: lane = b. Masks per-lane (1 global_load_ubyte/a, 64B/wave useful,
//  saddr form). Weights block-uniform -> s_load_dwordx16 (4/chunk, one
//  lgkmcnt per 4-a chunk, co-resident wave covers the stall). Inner loop:
//  cvt + mov + 8 v_pk_fma_f32 (weight pairs from consecutive SGPRs = the one
//  legal scalar src). LDS = 0, DS pipe = 0.
//  R8 lesson kept: graph = kernels only (init_kernel, no hipMemsetAsync).
// ---------------------------------------------------------------------------

#define N_CORES   64
#define NN        256
#define AA        256
#define BB        128
#define DIN       1024
#define NOUT      10
#define CYCLES    32
#define ROW_SPK   0u
#define ROW_A     32768u
#define ROW_B     49152u
#define ROW_ZERO  65536u
#define ROW_ONE   65537u

typedef float v2f  __attribute__((ext_vector_type(2)));
typedef float f16v __attribute__((ext_vector_type(16)));

__device__ __forceinline__ void tf_round(uint32_t& x0, uint32_t& x1, int r) {
    x0 += x1;
    x1 = (x1 << r) | (x1 >> (32 - r));
    x1 ^= x0;
}

__device__ __forceinline__ void threefry2x32(uint32_t k0, uint32_t k1,
                                             uint32_t c0, uint32_t c1,
                                             uint32_t& o0, uint32_t& o1) {
    uint32_t ks2 = k0 ^ k1 ^ 0x1BD11BDAu;
    uint32_t x0 = c0 + k0, x1 = c1 + k1;
    tf_round(x0,x1,13); tf_round(x0,x1,15); tf_round(x0,x1,26); tf_round(x0,x1,6);
    x0 += k1; x1 += ks2 + 1u;
    tf_round(x0,x1,17); tf_round(x0,x1,29); tf_round(x0,x1,16); tf_round(x0,x1,24);
    x0 += ks2; x1 += k0 + 2u;
    tf_round(x0,x1,13); tf_round(x0,x1,15); tf_round(x0,x1,26); tf_round(x0,x1,6);
    x0 += k0; x1 += k1 + 3u;
    tf_round(x0,x1,17); tf_round(x0,x1,29); tf_round(x0,x1,16); tf_round(x0,x1,24);
    x0 += k1; x1 += ks2 + 4u;
    tf_round(x0,x1,13); tf_round(x0,x1,15); tf_round(x0,x1,26); tf_round(x0,x1,6);
    x0 += ks2; x1 += k0 + 5u;
    o0 = x0; o1 = x1;
}

// All launch-time state init in ONE kernel (graph stays kernels-only).
__global__ void init_kernel(unsigned char* __restrict__ Pb,
                            float* __restrict__ memb,
                            float* __restrict__ out) {
    int idx = blockIdx.x * 256 + threadIdx.x;       // 2048 blocks -> 524288
    float4 z = {0.0f, 0.0f, 0.0f, 0.0f};
    *(float4*)(memb + (size_t)idx * 4) = z;                         // 8 MiB
    *(uint32_t*)(Pb + (size_t)ROW_A * 128 + (size_t)idx * 4) = 0u;  // 2 MiB
    if (idx < 32)
        *(uint32_t*)(Pb + (size_t)ROW_ZERO * 128 + idx * 4) = 0u;
    else if (idx < 64)
        *(uint32_t*)(Pb + (size_t)ROW_ONE * 128 + (idx - 32) * 4) = 0x01010101u;
    if (idx < BB * NOUT)
        out[idx] = 0.0f;
}

__global__ void spikes_kernel(const float* __restrict__ x,
                              unsigned char* __restrict__ Pb) {
    __shared__ unsigned char S[32 * 132];
    int bx  = blockIdx.x;        // 1024 = 32 t * 32 dblk
    int t   = bx >> 5;
    int d0  = (bx & 31) * 32;
    int tid = threadIdx.x;

    uint32_t k0, k1;
    threefry2x32(0u, 42u, 0u, (uint32_t)t, k0, k1);   // keys[t] = (w0, w1)

    #pragma unroll
    for (int k = 0; k < 16; ++k) {
        int e  = tid + k * 256;      // 0..4095 = 128 bb * 32 dl
        int bb = e >> 5;
        int dl = e & 31;
        int d  = d0 + dl;
        uint32_t f = (uint32_t)(bb * 1024 + d);
        uint32_t y0, y1;
        threefry2x32(k0, k1, 0u, f, y0, y1);
        uint32_t bits = y0 ^ y1;                      // xor-fold
        float u = __uint_as_float((bits >> 9) | 0x3f800000u) - 1.0f;
        S[dl * 132 + bb] = (u < x[bb * 1024 + d]) ? 1 : 0;
    }
    __syncthreads();

    int dl = tid >> 3;
    int bg = tid & 7;
    const uint32_t* Srow = (const uint32_t*)(S + dl * 132);
    uint4 v;
    v.x = Srow[bg * 4 + 0]; v.y = Srow[bg * 4 + 1];
    v.z = Srow[bg * 4 + 2]; v.w = Srow[bg * 4 + 3];
    size_t row = (size_t)t * 1024 + d0 + dl;
    *(uint4*)(Pb + row * 128 + bg * 16) = v;
}

// WT[c][a][n] = W[c][n][a]
__global__ void wt_kernel(const float* __restrict__ W, float* __restrict__ WT) {
    __shared__ float T[32][33];
    int bx = blockIdx.x;            // 4096 = 64 c * 8 tn * 8 ta
    int c  = bx >> 6;
    int tn = (bx >> 3) & 7;
    int ta = bx & 7;
    int tid = threadIdx.x;
    int r  = tid >> 3;
    int q4 = (tid & 7) * 4;

    const float* src = W + (size_t)c * 65536 + (size_t)(tn * 32 + r) * 256 + ta * 32 + q4;
    float4 v = *(const float4*)src;
    T[r][q4 + 0] = v.x; T[r][q4 + 1] = v.y; T[r][q4 + 2] = v.z; T[r][q4 + 3] = v.w;
    __syncthreads();

    float4 o;
    o.x = T[q4 + 0][r]; o.y = T[q4 + 1][r]; o.z = T[q4 + 2][r]; o.w = T[q4 + 3][r];
    float* dst = WT + (size_t)c * 65536 + (size_t)(ta * 32 + r) * 256 + tn * 32 + q4;
    *(float4*)dst = o;
}

__global__ void offtab_kernel(const int* __restrict__ axon,
                              const int* __restrict__ outsrc,
                              uint32_t* __restrict__ off_tab,
                              uint32_t* __restrict__ out_off) {
    int bx = blockIdx.x;
    int tid = threadIdx.x;
    if (bx < 2048) {
        int idx = bx * 256 + tid;          // [t][c*256+a]
        int t   = idx >> 14;
        int ca  = idx & 16383;
        int j   = axon[ca];
        uint32_t row;
        if (j < 1024)        row = (uint32_t)(t * 1024 + j);
        else if (j < 17408)  row = (((t & 1) == 0) ? ROW_A : ROW_B) + (uint32_t)(j - 1024);
        else                 row = (j == 17408) ? ROW_ZERO : ROW_ONE;
        off_tab[idx] = row * 128u;
    } else {
        for (int idx = tid; idx < CYCLES * NOUT; idx += 256) {
            int t = idx / NOUT, o = idx % NOUT;
            int j = outsrc[o];
            uint32_t row;
            if (j < 1024)        row = (uint32_t)(t * 1024 + j);
            else if (j < 17408)  row = (((t & 1) == 0) ? ROW_B : ROW_A) + (uint32_t)(j - 1024);
            else                 row = (j == 17408) ? ROW_ZERO : ROW_ONE;
            out_off[idx] = row * 128u;
        }
    }
}

// One cycle. 1024 blocks x 128 thr (2 waves) = (c, n-group of 16).
// tid = b. Weights: block-uniform f16v loads -> s_load_dwordx16 (4 per 4-a
// chunk, batched lgkm wait). Masks: per-lane global_load_ubyte from the
// pool row (saddr = uniform row offset, vaddr = tid). Inner per a:
// v_cvt_f32_ubyte0 + mov + 8 v_pk_fma_f32 (weight pair = consecutive SGPRs).
// Zero LDS, zero DS. Ascending-a chain per (n,b) -> bit-exact.
__global__ __launch_bounds__(128, 4) void core_kernel(
    const unsigned char* __restrict__ Pb,
    unsigned char* __restrict__ Pw,
    const float* __restrict__ WT,
    const uint32_t* __restrict__ off_t,
    float* __restrict__ memb,
    const float* __restrict__ thresholds,
    uint32_t wbyte_base,
    const uint32_t* __restrict__ out_off_prev,
    float* __restrict__ d_out,
    int do_out)
{
    int tid = threadIdx.x;              // = b
    int bx  = blockIdx.x;

    // fused out-update for the PREVIOUS cycle (reads current READ parity)
    if (do_out && bx == 0) {
        #pragma unroll
        for (int o = 0; o < NOUT; ++o) {
            uint32_t off = out_off_prev[o];
            d_out[tid * NOUT + o] += (float)Pb[off + (uint32_t)tid];
        }
    }

    // decode: 1024 = 8 xcd * 8 c-local * 16 ng  (c grouped per XCD for L2)
    int c  = (bx & 7) * 8 + ((bx >> 3) & 7);
    int n0 = (bx >> 6) * 16;            // 0..240

    const float*    wt   = WT + (size_t)c * 65536 + n0;   // block-uniform
    const uint32_t* offs = off_t + c * 256;               // block-uniform

    v2f acc[8];
    #pragma unroll
    for (int k = 0; k < 8; ++k) acc[k] = (v2f){0.0f, 0.0f};

#define FMA_A(WV, MF)                                                         \
    { v2f m2_ = (v2f){(MF), (MF)};                                            \
      _Pragma("unroll")                                                       \
      for (int k_ = 0; k_ < 8; ++k_) {                                        \
          v2f w2_ = (v2f){(WV)[2 * k_], (WV)[2 * k_ + 1]};                    \
          acc[k_] = __builtin_elementwise_fma(w2_, m2_, acc[k_]);             \
      } }

    for (int ag = 0; ag < 256; ag += 4) {
        uint4 ro = *(const uint4*)(offs + ag);           // uniform -> s_load
        // per-lane mask bytes (saddr-form ubyte loads, hoisted/vmcnt-counted)
        float mf0 = (float)Pb[ro.x + (uint32_t)tid];
        float mf1 = (float)Pb[ro.y + (uint32_t)tid];
        float mf2 = (float)Pb[ro.z + (uint32_t)tid];
        float mf3 = (float)Pb[ro.w + (uint32_t)tid];
        // block-uniform weights -> s_load_dwordx16 x4, one batched wait
        f16v w0 = *(const f16v*)(wt + (size_t)(ag + 0) * 256);
        f16v w1 = *(const f16v*)(wt + (size_t)(ag + 1) * 256);
        f16v w2 = *(const f16v*)(wt + (size_t)(ag + 2) * 256);
        f16v w3 = *(const f16v*)(wt + (size_t)(ag + 3) * 256);
        FMA_A(w0, mf0)
        FMA_A(w1, mf1)
        FMA_A(w2, mf2)
        FMA_A(w3, mf3)
    }
#undef FMA_A

    // ---- Epilogue: memb RMW + fired bytes (16 n-rows, lane = b) ----
    float thr = thresholds[c];
    #pragma unroll
    for (int k = 0; k < 8; ++k) {
        #pragma unroll
        for (int h = 0; h < 2; ++h) {
            int n = n0 + 2 * k + h;
            size_t idx = (size_t)(c * 256 + n) * 128 + tid;
            float a = (h == 0) ? acc[k].x : acc[k].y;
            float v = memb[idx] + a;                 // single rounded add
            bool fired = v > thr;
            memb[idx] = fired ? 0.0f : v;
            Pw[wbyte_base + idx] = fired ? (unsigned char)1 : (unsigned char)0;
        }
    }
}

__global__ void tail_kernel(const unsigned char* __restrict__ Pb,
                            const uint32_t* __restrict__ out_off31,
                            float* __restrict__ d_out) {
    int tid = threadIdx.x;
    if (tid < BB) {
        #pragma unroll
        for (int o = 0; o < NOUT; ++o) {
            uint32_t off = out_off31[o];
            d_out[tid * NOUT + o] += (float)Pb[off + (uint32_t)tid];
        }
    }
}

extern "C" void kernel_launch(void* const* d_in, const int* in_sizes, int n_in,
                              void* d_out_, int out_size, void* d_ws, size_t ws_size,
                              hipStream_t stream) {
    const float* x          = (const float*)d_in[0];
    const float* W          = (const float*)d_in[1];
    const float* thresholds = (const float*)d_in[2];
    const int*   axon       = (const int*)d_in[3];
    const int*   outsrc     = (const int*)d_in[4];
    // d_in[5] = cycles; fixed instance -> 32.

    if (ws_size < (size_t)45 * 1024 * 1024) return;

    unsigned char* ws      = (unsigned char*)d_ws;
    unsigned char* Pb      = ws;                                    // 8.4 MB
    float*         WT      = (float*)(ws + (size_t)(16u << 20));    // 16 MiB
    uint32_t*      off_tab = (uint32_t*)(ws + (size_t)(32u << 20)); // 2 MiB
    uint32_t*      out_off = (uint32_t*)(ws + (size_t)(32u << 20) + 2u * 1024u * 1024u);
    float*         memb    = (float*)(ws + (size_t)(36u << 20));    // 8 MiB
    float*         out     = (float*)d_out_;

    init_kernel<<<2048, 256, 0, stream>>>(Pb, memb, out);
    spikes_kernel<<<1024, 256, 0, stream>>>(x, Pb);
    wt_kernel<<<4096, 256, 0, stream>>>(W, WT);
    offtab_kernel<<<2049, 256, 0, stream>>>(axon, outsrc, off_tab, out_off);

    for (int t = 0; t < CYCLES; ++t) {
        uint32_t wrow = ((t & 1) == 0) ? ROW_B : ROW_A;   // write parity
        const uint32_t* oprev = out_off + (t > 0 ? (t - 1) * NOUT : 0);
        core_kernel<<<1024, 128, 0, stream>>>(
            Pb, Pb, WT, off_tab + (size_t)t * 16384, memb, thresholds,
            wrow * 128u, oprev, out, t > 0 ? 1 : 0);
    }
    tail_kernel<<<1, 128, 0, stream>>>(Pb, out_off + 31 * NOUT, out);
}